// Round 5
// baseline (87.716 us; speedup 1.0000x reference)
//
#include <hip/hip_runtime.h>
#include <cmath>

#define NROWS 524288
#define NBLOCKS (NROWS / 256)
#define EPS 1e-10f

typedef float f4 __attribute__((ext_vector_type(4)));
// align(4): lets us issue dwordx4 loads on 4B-aligned rows (o4, stride 36B)
typedef float f4u __attribute__((ext_vector_type(4), aligned(4)));

template <int N>
__device__ __forceinline__ float head_loss(const float* x, const float* lbl) {
    float m = -INFINITY;
    #pragma unroll
    for (int i = 0; i < N; ++i) m = fmaxf(m, x[i]);
    float e[N];
    float s = 0.f;
    #pragma unroll
    for (int i = 0; i < N; ++i) { e[i] = __expf(x[i] - m); s += e[i]; }
    float inv = 1.0f / s;
    float acc = 0.f;
    #pragma unroll
    for (int i = 0; i < N; ++i) acc += __logf(e[i] * inv + EPS) * lbl[i];
    return -acc;
}

// LDS: labels only (29696 B) -> 5 blocks/CU (20 waves, 62.5% cap).
// Final reduction fused via device-scope atomics + arrival counter in d_ws.
__global__ __launch_bounds__(256, 5) void fused_loss_kernel(
    const float* __restrict__ o1, const float* __restrict__ o2,
    const float* __restrict__ o3, const float* __restrict__ o4,
    const float* __restrict__ lbl, double* __restrict__ gsum,
    unsigned* __restrict__ gcnt, float* __restrict__ out) {
    __shared__ float slbl[256 * 29];   // 29696 B
    __shared__ double sacc[4];

    const int tid = threadIdx.x;
    const int wid = tid >> 6;
    const int lane = tid & 63;
    const size_t blk = blockIdx.x;

    // Wave-private label staging (64 rows = 464 float4, 16B-aligned base):
    // no block barrier needed — in-wave lgkmcnt orders ds_write -> ds_read.
    {
        const f4* src = reinterpret_cast<const f4*>(lbl + blk * (256 * 29)) + wid * 464;
        f4* dst = reinterpret_cast<f4*>(slbl) + wid * 464;
        #pragma unroll
        for (int k = 0; k < 7; ++k) dst[lane + 64 * k] = src[lane + 64 * k];
        if (lane < 16) dst[lane + 448] = src[lane + 448];  // 464 = 7*64 + 16
    }

    const size_t i = blk * 256 + tid;

    // head 1: 8 floats, 32B stride, 16B aligned -> two dwordx4
    float v1[8];
    {
        const f4* p = reinterpret_cast<const f4*>(o1 + i * 8);
        f4 a = p[0], b = p[1];
        v1[0] = a.x; v1[1] = a.y; v1[2] = a.z; v1[3] = a.w;
        v1[4] = b.x; v1[5] = b.y; v1[6] = b.z; v1[7] = b.w;
    }
    // heads 2,3: 6 floats, 24B stride, 8B aligned -> three dwordx2 each
    float v2[6], v3[6];
    {
        const float2* p = reinterpret_cast<const float2*>(o2 + i * 6);
        float2 a = p[0], b = p[1], c = p[2];
        v2[0] = a.x; v2[1] = a.y; v2[2] = b.x; v2[3] = b.y; v2[4] = c.x; v2[5] = c.y;
    }
    {
        const float2* p = reinterpret_cast<const float2*>(o3 + i * 6);
        float2 a = p[0], b = p[1], c = p[2];
        v3[0] = a.x; v3[1] = a.y; v3[2] = b.x; v3[3] = b.y; v3[4] = c.x; v3[5] = c.y;
    }
    // head 4: 9 floats, 36B stride -> two align-4 dwordx4 + one dword
    float v4[9];
    {
        const f4u* p = reinterpret_cast<const f4u*>(o4 + i * 9);
        f4u a = p[0], b = p[1];
        v4[0] = a.x; v4[1] = a.y; v4[2] = a.z; v4[3] = a.w;
        v4[4] = b.x; v4[5] = b.y; v4[6] = b.z; v4[7] = b.w;
        v4[8] = o4[i * 9 + 8];
    }

    const float* lrow = slbl + tid * 29;  // stride 29 (odd): 2-way bank alias, free

    float loss;
    loss  = head_loss<8>(v1, lrow + 0);
    loss += head_loss<6>(v2, lrow + 8);
    loss += head_loss<6>(v3, lrow + 14);
    loss += head_loss<9>(v4, lrow + 20);

    // wave64 shfl reduce in double -> LDS -> block partial
    double d = (double)loss;
    #pragma unroll
    for (int off = 32; off > 0; off >>= 1) d += __shfl_down(d, off);

    if (lane == 0) sacc[wid] = d;
    __syncthreads();
    if (tid == 0) {
        double part = sacc[0] + sacc[1] + sacc[2] + sacc[3];
        atomicAdd(gsum, part);              // device-scope, coherent across XCDs
        __threadfence();
        unsigned old = atomicAdd(gcnt, 1u); // arrival counter
        if (old == NBLOCKS - 1) {           // last block finalizes
            __threadfence();
            double s = atomicAdd(gsum, 0.0); // coherent read-back
            out[0] = (float)(s / (double)NROWS);
        }
    }
}

extern "C" void kernel_launch(void* const* d_in, const int* in_sizes, int n_in,
                              void* d_out, int out_size, void* d_ws, size_t ws_size,
                              hipStream_t stream) {
    const float* o1  = (const float*)d_in[0];
    const float* o2  = (const float*)d_in[1];
    const float* o3  = (const float*)d_in[2];
    const float* o4  = (const float*)d_in[3];
    const float* lbl = (const float*)d_in[4];
    double* gsum = (double*)d_ws;
    unsigned* gcnt = (unsigned*)((char*)d_ws + 8);

    // zero the 16B accumulator+counter region (graph-capture-legal async memset)
    hipMemsetAsync(d_ws, 0, 16, stream);
    fused_loss_kernel<<<NBLOCKS, 256, 0, stream>>>(o1, o2, o3, o4, lbl,
                                                   gsum, gcnt, (float*)d_out);
}

// Round 8
// 44.701 us; speedup vs baseline: 1.9623x; 1.9623x over previous
//
#include <hip/hip_runtime.h>
#include <cmath>

#define NROWS 524288
#define NBLOCKS (NROWS / 256)
#define EPS 1e-10f

typedef float f4 __attribute__((ext_vector_type(4)));
// aligned(4): emit dwordx4 on 4B-aligned row bases (o2/o3/o4 strides 24/24/36 B)
typedef float f4u __attribute__((ext_vector_type(4), aligned(4)));

template <int N>
__device__ __forceinline__ float head_loss(const float* x, const float* lbl) {
    float m = -INFINITY;
    #pragma unroll
    for (int i = 0; i < N; ++i) m = fmaxf(m, x[i]);
    float e[N];
    float s = 0.f;
    #pragma unroll
    for (int i = 0; i < N; ++i) { e[i] = __expf(x[i] - m); s += e[i]; }
    float inv = 1.0f / s;
    float acc = 0.f;
    #pragma unroll
    for (int i = 0; i < N; ++i) acc += __logf(e[i] * inv + EPS) * lbl[i];
    return -acc;
}

// Single compute dispatch (+ 4B memset). Cross-block protocol, all RMW:
//  - writer: atomicExch partial[blk] (RMW -> coherence point, overwrites stale ws)
//  - manual s_waitcnt vmcnt(0): exchange ACK'd at coherence point before arrival
//    (NOT a release fence / __threadfence -> no L2 writeback/invalidate, which
//    was R5's 87us disaster)
//  - counter: fetch_add; memset to 0 each call so old==NBLOCKS-1 IS the last
//    arriver (R7 bug: poison start 682 made the detector fire 682 blocks early)
//  - reader: fetch_add(+0.0) RMW reads at the coherence point (never stale L2)
// Deterministic: partials are pure f(inputs); last block sums slots in fixed
// index order; +0.0 RMWs don't perturb values.
__global__ __launch_bounds__(256, 5) void fused_loss_kernel(
    const float* __restrict__ o1, const float* __restrict__ o2,
    const float* __restrict__ o3, const float* __restrict__ o4,
    const float* __restrict__ lbl, double* partial,
    unsigned* gcnt, float* out) {
    __shared__ float slbl[256 * 29];   // 29696 B -> 5 blocks/CU
    __shared__ double sacc[4];
    __shared__ int slast;

    const int tid = threadIdx.x;
    const int wid = tid >> 6;
    const int lane = tid & 63;
    const size_t blk = blockIdx.x;

    // Wave-private label staging (64 rows = 464 float4, 16B-aligned base):
    // in-wave lgkmcnt orders ds_write -> ds_read, no block barrier needed.
    {
        const f4* src = reinterpret_cast<const f4*>(lbl + blk * (256 * 29)) + wid * 464;
        f4* dst = reinterpret_cast<f4*>(slbl) + wid * 464;
        #pragma unroll
        for (int k = 0; k < 7; ++k) dst[lane + 64 * k] = src[lane + 64 * k];
        if (lane < 16) dst[lane + 448] = src[lane + 448];  // 464 = 7*64 + 16
    }

    const size_t i = blk * 256 + tid;

    // head 1: 8 floats, 32B stride, 16B aligned -> two dwordx4
    float v1[8];
    {
        const f4* p = reinterpret_cast<const f4*>(o1 + i * 8);
        f4 a = p[0], b = p[1];
        v1[0] = a.x; v1[1] = a.y; v1[2] = a.z; v1[3] = a.w;
        v1[4] = b.x; v1[5] = b.y; v1[6] = b.z; v1[7] = b.w;
    }
    // heads 2,3: 6 floats, 24B stride -> dwordx4 (4B-align ok) + dwordx2
    float v2[6], v3[6];
    {
        f4u a = *reinterpret_cast<const f4u*>(o2 + i * 6);
        float2 b = *reinterpret_cast<const float2*>(o2 + i * 6 + 4);
        v2[0] = a.x; v2[1] = a.y; v2[2] = a.z; v2[3] = a.w; v2[4] = b.x; v2[5] = b.y;
    }
    {
        f4u a = *reinterpret_cast<const f4u*>(o3 + i * 6);
        float2 b = *reinterpret_cast<const float2*>(o3 + i * 6 + 4);
        v3[0] = a.x; v3[1] = a.y; v3[2] = a.z; v3[3] = a.w; v3[4] = b.x; v3[5] = b.y;
    }
    // head 4: 9 floats, 36B stride -> two 4B-aligned dwordx4 + one dword
    float v4[9];
    {
        f4u a = *reinterpret_cast<const f4u*>(o4 + i * 9);
        f4u b = *reinterpret_cast<const f4u*>(o4 + i * 9 + 4);
        v4[0] = a.x; v4[1] = a.y; v4[2] = a.z; v4[3] = a.w;
        v4[4] = b.x; v4[5] = b.y; v4[6] = b.z; v4[7] = b.w;
        v4[8] = o4[i * 9 + 8];
    }

    const float* lrow = slbl + tid * 29;  // stride 29 (odd): 2-way bank alias, free

    float loss;
    loss  = head_loss<8>(v1, lrow + 0);
    loss += head_loss<6>(v2, lrow + 8);
    loss += head_loss<6>(v3, lrow + 14);
    loss += head_loss<9>(v4, lrow + 20);

    // wave64 shfl reduce in double -> LDS -> block partial
    double d = (double)loss;
    #pragma unroll
    for (int off = 32; off > 0; off >>= 1) d += __shfl_down(d, off);

    if (lane == 0) sacc[wid] = d;
    __syncthreads();
    if (tid == 0) {
        double part = sacc[0] + sacc[1] + sacc[2] + sacc[3];
        (void)__hip_atomic_exchange(&partial[blk], part, __ATOMIC_RELAXED,
                                    __HIP_MEMORY_SCOPE_AGENT);
        // exchange completion ack'd before we announce arrival (no cache ops)
        asm volatile("s_waitcnt vmcnt(0)" ::: "memory");
        unsigned old = __hip_atomic_fetch_add(gcnt, 1u, __ATOMIC_RELAXED,
                                              __HIP_MEMORY_SCOPE_AGENT);
        slast = (old == NBLOCKS - 1) ? 1 : 0;
    }
    __syncthreads();

    if (slast) {  // block-uniform; genuinely the last arriver (counter starts 0)
        double s = 0.0;
        #pragma unroll
        for (int k = 0; k < NBLOCKS / 256; ++k)
            s += __hip_atomic_fetch_add(&partial[tid + 256 * k], 0.0,
                                        __ATOMIC_RELAXED, __HIP_MEMORY_SCOPE_AGENT);
        #pragma unroll
        for (int off = 32; off > 0; off >>= 1) s += __shfl_down(s, off);
        if (lane == 0) sacc[wid] = s;
        __syncthreads();
        if (tid == 0)
            out[0] = (float)((sacc[0] + sacc[1] + sacc[2] + sacc[3]) / (double)NROWS);
    }
}

extern "C" void kernel_launch(void* const* d_in, const int* in_sizes, int n_in,
                              void* d_out, int out_size, void* d_ws, size_t ws_size,
                              hipStream_t stream) {
    const float* o1  = (const float*)d_in[0];
    const float* o2  = (const float*)d_in[1];
    const float* o3  = (const float*)d_in[2];
    const float* o4  = (const float*)d_in[3];
    const float* lbl = (const float*)d_in[4];
    double* partial = (double*)d_ws;                      // 2048 doubles, RMW-written
    unsigned* gcnt  = (unsigned*)((char*)d_ws + 16384);   // own line

    // zero ONLY the counter (4B) so the last-arriver detector is exact
    hipMemsetAsync(gcnt, 0, 4, stream);
    fused_loss_kernel<<<NBLOCKS, 256, 0, stream>>>(o1, o2, o3, o4, lbl,
                                                   partial, gcnt, (float*)d_out);
}

// Round 9
// 31.238 us; speedup vs baseline: 2.8080x; 1.4310x over previous
//
#include <hip/hip_runtime.h>
#include <cmath>

#define NROWS 524288
#define NBLOCKS (NROWS / 256)
#define EPS 1e-10f

typedef float f4 __attribute__((ext_vector_type(4)));
// aligned(4): emit dwordx4 on 4B-aligned row bases (o2/o3/o4 strides 24/24/36 B)
typedef float f4u __attribute__((ext_vector_type(4), aligned(4)));

template <int N>
__device__ __forceinline__ float head_loss(const float* x, const float* lbl) {
    float m = -INFINITY;
    #pragma unroll
    for (int i = 0; i < N; ++i) m = fmaxf(m, x[i]);
    float e[N];
    float s = 0.f;
    #pragma unroll
    for (int i = 0; i < N; ++i) { e[i] = __expf(x[i] - m); s += e[i]; }
    float inv = 1.0f / s;
    float acc = 0.f;
    #pragma unroll
    for (int i = 0; i < N; ++i) acc += __logf(e[i] * inv + EPS) * lbl[i];
    return -acc;
}

// Single compute dispatch (+4160B memset). R8 lesson: 2048 same-address RMWs
// serialize at ~20ns each => +16us. Fix: hierarchical arrival.
//  level-1: 64 counters on SEPARATE 64B lines (bid&63) -> 32 arrivals/line
//  level-2: 1 counter, only 64 arrivals (group-lasts)
// All cross-block data via RMW (exch write / fetch_add(+0.0) read) at the
// coherence point — no reliance on cross-XCD L2 coherence, no cache-flushing
// fences (R5's 87us). vmcnt(0) orders own-exch-ack before arrival announce.
// Tail: waves 1-3 exit after one barrier; wave 0 handles arrival + (if last)
// the fixed-order reduce of 2048 partials -> deterministic output.
__global__ __launch_bounds__(256, 5) void fused_loss_kernel(
    const float* __restrict__ o1, const float* __restrict__ o2,
    const float* __restrict__ o3, const float* __restrict__ o4,
    const float* __restrict__ lbl, double* partial,
    unsigned* gcnt, float* out) {
    __shared__ float slbl[256 * 29];   // 29696 B -> 5 blocks/CU
    __shared__ double sacc[4];

    const int tid = threadIdx.x;
    const int wid = tid >> 6;
    const int lane = tid & 63;
    const size_t blk = blockIdx.x;

    // Wave-private label staging (64 rows = 464 float4, 16B-aligned base):
    // in-wave lgkmcnt orders ds_write -> ds_read, no block barrier needed.
    {
        const f4* src = reinterpret_cast<const f4*>(lbl + blk * (256 * 29)) + wid * 464;
        f4* dst = reinterpret_cast<f4*>(slbl) + wid * 464;
        #pragma unroll
        for (int k = 0; k < 7; ++k) dst[lane + 64 * k] = src[lane + 64 * k];
        if (lane < 16) dst[lane + 448] = src[lane + 448];  // 464 = 7*64 + 16
    }

    const size_t i = blk * 256 + tid;

    // head 1: 8 floats, 32B stride, 16B aligned -> two dwordx4
    float v1[8];
    {
        const f4* p = reinterpret_cast<const f4*>(o1 + i * 8);
        f4 a = p[0], b = p[1];
        v1[0] = a.x; v1[1] = a.y; v1[2] = a.z; v1[3] = a.w;
        v1[4] = b.x; v1[5] = b.y; v1[6] = b.z; v1[7] = b.w;
    }
    // heads 2,3: 6 floats, 24B stride -> dwordx4 (4B-align ok) + dwordx2
    float v2[6], v3[6];
    {
        f4u a = *reinterpret_cast<const f4u*>(o2 + i * 6);
        float2 b = *reinterpret_cast<const float2*>(o2 + i * 6 + 4);
        v2[0] = a.x; v2[1] = a.y; v2[2] = a.z; v2[3] = a.w; v2[4] = b.x; v2[5] = b.y;
    }
    {
        f4u a = *reinterpret_cast<const f4u*>(o3 + i * 6);
        float2 b = *reinterpret_cast<const float2*>(o3 + i * 6 + 4);
        v3[0] = a.x; v3[1] = a.y; v3[2] = a.z; v3[3] = a.w; v3[4] = b.x; v3[5] = b.y;
    }
    // head 4: 9 floats, 36B stride -> two 4B-aligned dwordx4 + one dword
    float v4[9];
    {
        f4u a = *reinterpret_cast<const f4u*>(o4 + i * 9);
        f4u b = *reinterpret_cast<const f4u*>(o4 + i * 9 + 4);
        v4[0] = a.x; v4[1] = a.y; v4[2] = a.z; v4[3] = a.w;
        v4[4] = b.x; v4[5] = b.y; v4[6] = b.z; v4[7] = b.w;
        v4[8] = o4[i * 9 + 8];
    }

    const float* lrow = slbl + tid * 29;  // stride 29 (odd): 2-way bank alias, free

    float loss;
    loss  = head_loss<8>(v1, lrow + 0);
    loss += head_loss<6>(v2, lrow + 8);
    loss += head_loss<6>(v3, lrow + 14);
    loss += head_loss<9>(v4, lrow + 20);

    // wave64 shfl reduce in double -> LDS
    double d = (double)loss;
    #pragma unroll
    for (int off = 32; off > 0; off >>= 1) d += __shfl_down(d, off);

    if (lane == 0) sacc[wid] = d;
    __syncthreads();
    if (wid != 0) return;  // waves 1-3 done; no further barriers below

    // ---- wave 0 only ----
    double part = sacc[0] + sacc[1] + sacc[2] + sacc[3];
    int slast = 0;
    if (lane == 0) {
        // RMW push of this block's partial (distinct address per block: cheap)
        (void)__hip_atomic_exchange(&partial[blk], part, __ATOMIC_RELAXED,
                                    __HIP_MEMORY_SCOPE_AGENT);
        // exchange ack'd at coherence point before announcing arrival
        asm volatile("s_waitcnt vmcnt(0)" ::: "memory");
        unsigned* c1 = gcnt + (blk & 63) * 16;  // own 64B line per group
        unsigned old1 = __hip_atomic_fetch_add(c1, 1u, __ATOMIC_RELAXED,
                                               __HIP_MEMORY_SCOPE_AGENT);
        if (old1 == 31) {  // last of this 32-block group (c1 memset to 0)
            unsigned old2 = __hip_atomic_fetch_add(gcnt + 1024, 1u, __ATOMIC_RELAXED,
                                                   __HIP_MEMORY_SCOPE_AGENT);
            slast = (old2 == 63);  // last group overall
        }
    }
    slast = __shfl(slast, 0);  // wave-uniform, no barrier needed

    if (slast) {  // exactly one block; all 2048 exchanges are ack'd by protocol
        double s = 0.0;
        #pragma unroll
        for (int k = 0; k < NBLOCKS / 64; ++k)  // fixed order -> deterministic
            s += __hip_atomic_fetch_add(&partial[lane + 64 * k], 0.0,
                                        __ATOMIC_RELAXED, __HIP_MEMORY_SCOPE_AGENT);
        #pragma unroll
        for (int off = 32; off > 0; off >>= 1) s += __shfl_down(s, off);
        if (lane == 0) out[0] = (float)(s / (double)NROWS);
    }
}

extern "C" void kernel_launch(void* const* d_in, const int* in_sizes, int n_in,
                              void* d_out, int out_size, void* d_ws, size_t ws_size,
                              hipStream_t stream) {
    const float* o1  = (const float*)d_in[0];
    const float* o2  = (const float*)d_in[1];
    const float* o3  = (const float*)d_in[2];
    const float* o4  = (const float*)d_in[3];
    const float* lbl = (const float*)d_in[4];
    double* partial = (double*)d_ws;                      // 2048 doubles, RMW-written
    unsigned* gcnt  = (unsigned*)((char*)d_ws + 16384);   // 64 lines + 1 line

    // zero the arrival counters: 64*64B (level-1) + 64B (level-2)
    hipMemsetAsync(gcnt, 0, 4160, stream);
    fused_loss_kernel<<<NBLOCKS, 256, 0, stream>>>(o1, o2, o3, o4, lbl,
                                                   partial, gcnt, (float*)d_out);
}

// Round 10
// 28.640 us; speedup vs baseline: 3.0627x; 1.0907x over previous
//
#include <hip/hip_runtime.h>
#include <cmath>

#define NROWS 524288
#define NBLOCKS (NROWS / 256)
#define EPS 1e-10f

template <int N>
__device__ __forceinline__ float head_loss(const float* x, const float* lbl) {
    float m = -INFINITY;
    #pragma unroll
    for (int i = 0; i < N; ++i) m = fmaxf(m, x[i]);
    float e[N];
    float s = 0.f;
    #pragma unroll
    for (int i = 0; i < N; ++i) { e[i] = __expf(x[i] - m); s += e[i]; }
    float inv = 1.0f / s;
    float acc = 0.f;
    #pragma unroll
    for (int i = 0; i < N; ++i) acc += __logf(e[i] * inv + EPS) * lbl[i];
    return -acc;
}

// LDS: labels only (29 floats/row) -> 29696 B/block -> 5 blocks/CU (62.5% cap).
// Best measured structure (R3: 28.696 us, twice). Fused single-dispatch
// variants (R5/R8/R9) all regressed: same-address RMW serialization or
// elected-reduce tail on the critical path. Two-kernel + per-block partials
// is the floor for this memory-service-bound access mix.
__global__ __launch_bounds__(256, 5) void fused_loss_kernel(
    const float* __restrict__ o1, const float* __restrict__ o2,
    const float* __restrict__ o3, const float* __restrict__ o4,
    const float* __restrict__ lbl, double* __restrict__ partial) {
    __shared__ float slbl[256 * 29];   // 29696 B
    __shared__ double sacc[4];

    const int tid = threadIdx.x;
    const int wid = tid >> 6;
    const int lane = tid & 63;
    const size_t blk = blockIdx.x;

    // Wave-private label staging: wave w stages exactly its own 64 rows
    // (464 float4 = 7424 B, 16B-aligned), so no __syncthreads is needed —
    // in-wave LDS ordering (lgkmcnt) guarantees read-after-write.
    {
        const float4* src = reinterpret_cast<const float4*>(lbl + blk * (256 * 29)) + wid * 464;
        float4* dst = reinterpret_cast<float4*>(slbl) + wid * 464;
        #pragma unroll
        for (int k = 0; k < 7; ++k) dst[lane + 64 * k] = src[lane + 64 * k];
        if (lane < 16) dst[lane + 448] = src[lane + 448];  // 464 = 7*64 + 16
    }

    const size_t i = blk * 256 + tid;

    // head 1: 8 floats, 32B stride, 16B aligned -> two float4
    float v1[8];
    {
        const float4* p = reinterpret_cast<const float4*>(o1 + i * 8);
        float4 a = p[0], b = p[1];
        v1[0] = a.x; v1[1] = a.y; v1[2] = a.z; v1[3] = a.w;
        v1[4] = b.x; v1[5] = b.y; v1[6] = b.z; v1[7] = b.w;
    }
    // heads 2,3: 6 floats, 24B stride, 8B aligned -> three float2
    float v2[6], v3[6];
    {
        const float2* p = reinterpret_cast<const float2*>(o2 + i * 6);
        float2 a = p[0], b = p[1], c = p[2];
        v2[0] = a.x; v2[1] = a.y; v2[2] = b.x; v2[3] = b.y; v2[4] = c.x; v2[5] = c.y;
    }
    {
        const float2* p = reinterpret_cast<const float2*>(o3 + i * 6);
        float2 a = p[0], b = p[1], c = p[2];
        v3[0] = a.x; v3[1] = a.y; v3[2] = b.x; v3[3] = b.y; v3[4] = c.x; v3[5] = c.y;
    }
    // head 4: 9 floats, 36B stride -> scalar loads (each 64B line fully used
    // across the wave's lanes; latency hidden by occupancy)
    float v4[9];
    {
        const float* p = o4 + i * 9;
        #pragma unroll
        for (int j = 0; j < 9; ++j) v4[j] = p[j];
    }

    const float* lrow = slbl + tid * 29;  // stride 29 (odd): 2-way bank alias, free

    float loss;
    loss  = head_loss<8>(v1, lrow + 0);
    loss += head_loss<6>(v2, lrow + 8);
    loss += head_loss<6>(v3, lrow + 14);
    loss += head_loss<9>(v4, lrow + 20);

    // wave64 shfl reduce in double -> LDS -> per-block partial (no atomics)
    double d = (double)loss;
    #pragma unroll
    for (int off = 32; off > 0; off >>= 1) d += __shfl_down(d, off);

    if (lane == 0) sacc[wid] = d;
    __syncthreads();
    if (tid == 0) partial[blk] = sacc[0] + sacc[1] + sacc[2] + sacc[3];
}

__global__ __launch_bounds__(256) void reduce_kernel(const double* __restrict__ partial,
                                                     float* __restrict__ out) {
    double s = 0.0;
    for (int i = threadIdx.x; i < NBLOCKS; i += 256) s += partial[i];
    #pragma unroll
    for (int off = 32; off > 0; off >>= 1) s += __shfl_down(s, off);
    __shared__ double sa[4];
    const int wid = threadIdx.x >> 6;
    if ((threadIdx.x & 63) == 0) sa[wid] = s;
    __syncthreads();
    if (threadIdx.x == 0) out[0] = (float)((sa[0] + sa[1] + sa[2] + sa[3]) / (double)NROWS);
}

extern "C" void kernel_launch(void* const* d_in, const int* in_sizes, int n_in,
                              void* d_out, int out_size, void* d_ws, size_t ws_size,
                              hipStream_t stream) {
    const float* o1  = (const float*)d_in[0];
    const float* o2  = (const float*)d_in[1];
    const float* o3  = (const float*)d_in[2];
    const float* o4  = (const float*)d_in[3];
    const float* lbl = (const float*)d_in[4];
    double* partial = (double*)d_ws;  // NBLOCKS doubles, fully overwritten each call

    fused_loss_kernel<<<NBLOCKS, 256, 0, stream>>>(o1, o2, o3, o4, lbl, partial);
    reduce_kernel<<<1, 256, 0, stream>>>(partial, (float*)d_out);
}